// Round 5
// baseline (131.351 us; speedup 1.0000x reference)
//
#include <hip/hip_runtime.h>
#include <hip/hip_bf16.h>

// NT-Xent (SimCLR) loss, B=4096, D=256, N=8192, T=0.5.
// loss = [ sum_i log(sum_{j!=i} exp(sim_ij * 2)) - 4 * sum_{i<B} pos_i ] / N
// sim symmetric: upper-triangle 128x128 tiles only (2080 of 4096). Each tile
// emits row-sums for BOTH its row-range (DPP lane reduce -> colacc) and its
// col-range (per-lane reg reduce).
// NO LDS STAGING: Z (4 MB) is L2-resident; per chunk each row's fragments are
// one 64B line read by 2 lanes -> L1/L2 serve it cheaper than the LDS pipe
// (which was the measured bottleneck: ~2050 DS-cyc vs 1033 MFMA-cyc per
// chunk-round). Waves are fully independent: zero k-loop barriers.

constexpr int BB = 4096;                 // batch
constexpr int NN = 8192;                 // 2*batch
constexpr int DD = 256;                  // feature dim
constexpr int TS = 128;                  // tile edge
constexpr int NT = NN / TS;              // 64 tile rows/cols
constexpr int NBLK = NT * (NT + 1) / 2;  // 2080 = 8*260
constexpr int KSTEPS = DD / 16;          // 16 MFMA k-steps

typedef _Float16 half4v __attribute__((ext_vector_type(4)));
typedef _Float16 half8v __attribute__((ext_vector_type(8)));
typedef float floatx16 __attribute__((ext_vector_type(16)));

// ---------------- Kernel 1: normalize rows -> f16, pos partials, zero rowsum -
__global__ __launch_bounds__(256) void nt_normalize(
    const float* __restrict__ zi, const float* __restrict__ zj,
    _Float16* __restrict__ Z, float* __restrict__ posPartial,
    float* __restrict__ rowsum)
{
    const int lane = threadIdx.x & 63;
    const int wave = threadIdx.x >> 6;
    const int i = blockIdx.x * 4 + wave;   // pair index, < BB

    if (blockIdx.x < 32) rowsum[blockIdx.x * 256 + threadIdx.x] = 0.f;

    const float4 a = ((const float4*)(zi + (size_t)i * DD))[lane];
    const float4 b = ((const float4*)(zj + (size_t)i * DD))[lane];

    float ssi = a.x*a.x + a.y*a.y + a.z*a.z + a.w*a.w;
    float ssj = b.x*b.x + b.y*b.y + b.z*b.z + b.w*b.w;
    float dd  = a.x*b.x + a.y*b.y + a.z*b.z + a.w*b.w;
#pragma unroll
    for (int off = 32; off > 0; off >>= 1) {
        ssi += __shfl_xor(ssi, off);
        ssj += __shfl_xor(ssj, off);
        dd  += __shfl_xor(dd,  off);
    }
    const float invi = rsqrtf(ssi);
    const float invj = rsqrtf(ssj);

    half4v ha, hb;
    ha.x = (_Float16)(a.x * invi); ha.y = (_Float16)(a.y * invi);
    ha.z = (_Float16)(a.z * invi); ha.w = (_Float16)(a.w * invi);
    hb.x = (_Float16)(b.x * invj); hb.y = (_Float16)(b.y * invj);
    hb.z = (_Float16)(b.z * invj); hb.w = (_Float16)(b.w * invj);

    ((half4v*)(Z + (size_t)i * DD))[lane]        = ha;
    ((half4v*)(Z + (size_t)(BB + i) * DD))[lane] = hb;

    __shared__ float ps[4];
    if (lane == 0) ps[wave] = dd * invi * invj;
    __syncthreads();
    if (threadIdx.x == 0)
        posPartial[blockIdx.x] = ps[0] + ps[1] + ps[2] + ps[3];
}

// DPP half-wave reduce: lane31 = sum(lanes 0..31), lane63 = sum(lanes 32..63).
__device__ __forceinline__ float half_sums(float x) {
    int t;
    t = __builtin_amdgcn_update_dpp(0, __builtin_bit_cast(int, x), 0x111, 0xf, 0xf, false);
    x += __builtin_bit_cast(float, t);
    t = __builtin_amdgcn_update_dpp(0, __builtin_bit_cast(int, x), 0x112, 0xf, 0xf, false);
    x += __builtin_bit_cast(float, t);
    t = __builtin_amdgcn_update_dpp(0, __builtin_bit_cast(int, x), 0x114, 0xf, 0xf, false);
    x += __builtin_bit_cast(float, t);
    t = __builtin_amdgcn_update_dpp(0, __builtin_bit_cast(int, x), 0x118, 0xf, 0xf, false);
    x += __builtin_bit_cast(float, t);
    t = __builtin_amdgcn_update_dpp(0, __builtin_bit_cast(int, x), 0x142, 0xa, 0xf, false);
    x += __builtin_bit_cast(float, t);
    return x;
}

// ---------------- Kernel 2: upper-tri sim-GEMM + exp + row/col sums ----------
// Grid: 2080 blocks x 256 thr (4 waves). Block (rt,ct): 128x128 tile.
// Wave (wr,wc) computes a 64x64 quadrant: 2x2 32x32 MFMA tiles (64 acc VGPR).
// Fragments loaded directly from global (L1/L2-served); no LDS in the k-loop.
// 16 waves/CU (VGPR <= 128 via launch_bounds(256,4)) hide the L2 latency.
__global__ __launch_bounds__(256, 4) void nt_simexp(
    const _Float16* __restrict__ Z, float* __restrict__ rowsum)
{
    __shared__ float colacc[TS];               // 512 B (only LDS use)

    // Bijective XCD swizzle (2080 % 8 == 0).
    const int bid = (blockIdx.x & 7) * (NBLK / 8) + (blockIdx.x >> 3);

    // Closed-form reverse-triangular map: t counts from the bottom row.
    const int t = NBLK - 1 - bid;
    int m = (int)((sqrtf((float)(8 * t + 1)) - 1.0f) * 0.5f);
    while ((m + 1) * (m + 2) / 2 <= t) ++m;   // fixup (+-1 from sqrt rounding)
    while (m * (m + 1) / 2 > t) --m;
    const int rt = NT - 1 - m;
    const int ct = NT - 1 - (t - m * (m + 1) / 2);
    const bool diag = (rt == ct);

    const int tid = threadIdx.x;
    const int wave = tid >> 6;
    const int lane = tid & 63;
    const int lm = lane & 31;
    const int lh = lane >> 5;
    const int wr = wave >> 1;           // row half (A side)
    const int wc = wave & 1;            // col half (B side)

    const int rbase = rt * TS;          // A-side rows (output rows)
    const int cbase = ct * TS;          // B-side rows (output cols)

    if (tid < TS) colacc[tid] = 0.f;
    __syncthreads();                    // colacc init visible before epilogue

    // Per-lane fragment row pointers. MFMA 32x32x16 A/B layout: lane (lm,lh)
    // holds row/col lm, k = 16*ks + lh*8 + j (j=0..7)  [verified r0-r4].
    const _Float16* ar0 = Z + (size_t)(rbase + wr * 64 + lm) * DD + lh * 8;
    const _Float16* ar1 = ar0 + 32 * DD;
    const _Float16* br0 = Z + (size_t)(cbase + wc * 64 + lm) * DD + lh * 8;
    const _Float16* br1 = br0 + 32 * DD;

    floatx16 a00, a01, a10, a11;
#pragma unroll
    for (int r = 0; r < 16; ++r) { a00[r] = 0.f; a01[r] = 0.f; a10[r] = 0.f; a11[r] = 0.f; }

#pragma unroll
    for (int ks = 0; ks < KSTEPS; ++ks) {
        const int off = ks * 16;
        half8v fa0 = *(const half8v*)(ar0 + off);
        half8v fa1 = *(const half8v*)(ar1 + off);
        half8v fb0 = *(const half8v*)(br0 + off);
        half8v fb1 = *(const half8v*)(br1 + off);
        a00 = __builtin_amdgcn_mfma_f32_32x32x16_f16(fa0, fb0, a00, 0, 0, 0);
        a01 = __builtin_amdgcn_mfma_f32_32x32x16_f16(fa0, fb1, a01, 0, 0, 0);
        a10 = __builtin_amdgcn_mfma_f32_32x32x16_f16(fa1, fb0, a10, 0, 0, 0);
        a11 = __builtin_amdgcn_mfma_f32_32x32x16_f16(fa1, fb1, a11, 0, 0, 0);
    }

    // Epilogue: e = exp2(sim * 2*log2e). Per-lane reg sums -> col-range rows
    // (B side, index lm); DPP across lm -> row-range rows (A side, index mrow).
    const float KEXP = 2.0f * 1.44269504088896340736f;
    float eb0 = 0.f, eb1 = 0.f;
#pragma unroll
    for (int tr = 0; tr < 2; ++tr) {
#pragma unroll
        for (int r = 0; r < 16; ++r) {
            const int mrow = (r & 3) + 8 * (r >> 2) + 4 * lh;
            float e0 = __builtin_amdgcn_exp2f((tr ? a10[r] : a00[r]) * KEXP);
            float e1 = __builtin_amdgcn_exp2f((tr ? a11[r] : a01[r]) * KEXP);
            // Diagonal element: global row == col -> wr==wc, tr==tc, mrow==lm.
            // e0 carries tc=0 (zero when tr==0), e1 carries tc=1 (when tr==1).
            if (diag && (wr == wc) && (mrow == lm)) {
                if (tr == 0) e0 = 0.f; else e1 = 0.f;
            }
            eb0 += e0; eb1 += e1;
            if (!diag) {
                float s2 = half_sums(e0 + e1);   // lanes 31/63 hold half-sums
                if (lm == 31)
                    atomicAdd(&colacc[wr * 64 + tr * 32 + mrow], s2);  // ds_add
            }
        }
    }

    eb0 += __shfl_xor(eb0, 32);
    eb1 += __shfl_xor(eb1, 32);
    if (lane < 32) {
        atomicAdd(&rowsum[cbase + wc * 64 + lm], eb0);
        atomicAdd(&rowsum[cbase + wc * 64 + 32 + lm], eb1);
    }
    if (!diag) {
        __syncthreads();
        if (tid < TS) atomicAdd(&rowsum[rbase + tid], colacc[tid]);
    }
}

// ---------------- Kernel 3: finalize ----------------------------------------
__global__ __launch_bounds__(256) void nt_finalize(
    const float* __restrict__ rowsum, const float* __restrict__ posPartial,
    float* __restrict__ out)
{
    const int tid = threadIdx.x;
    float acc = 0.f;
#pragma unroll
    for (int it = 0; it < NN / 256; ++it)
        acc += __builtin_amdgcn_logf(rowsum[tid + it * 256]);   // log2
    float pacc = 0.f;
#pragma unroll
    for (int it = 0; it < 4; ++it)
        pacc += posPartial[tid + it * 256];

#pragma unroll
    for (int off = 32; off > 0; off >>= 1) {
        acc  += __shfl_xor(acc,  off);
        pacc += __shfl_xor(pacc, off);
    }
    __shared__ float sa[4], sp[4];
    const int wave = tid >> 6;
    if ((tid & 63) == 0) { sa[wave] = acc; sp[wave] = pacc; }
    __syncthreads();
    if (tid == 0) {
        const float lntot = (sa[0] + sa[1] + sa[2] + sa[3]) * 0.6931471805599453f;
        const float ptot  = sp[0] + sp[1] + sp[2] + sp[3];
        out[0] = (lntot - 4.0f * ptot) * (1.0f / (float)NN);
    }
}

// ---------------- Launch ------------------------------------------------------
extern "C" void kernel_launch(void* const* d_in, const int* in_sizes, int n_in,
                              void* d_out, int out_size, void* d_ws, size_t ws_size,
                              hipStream_t stream) {
    const float* zi = (const float*)d_in[0];
    const float* zj = (const float*)d_in[1];
    float* out = (float*)d_out;

    _Float16* Z = (_Float16*)d_ws;                                  // 4 MB
    float* rowsum = (float*)((char*)d_ws + (size_t)NN * DD * 2);    // 32 KB
    float* posPartial = rowsum + NN;                                // 4 KB

    nt_normalize<<<BB / 4, 256, 0, stream>>>(zi, zj, Z, posPartial, rowsum);
    nt_simexp<<<NBLK, 256, 0, stream>>>((const _Float16*)Z, rowsum);
    nt_finalize<<<1, 256, 0, stream>>>(rowsum, posPartial, out);
}

// Round 6
// 117.986 us; speedup vs baseline: 1.1133x; 1.1133x over previous
//
#include <hip/hip_runtime.h>
#include <hip/hip_bf16.h>

// NT-Xent (SimCLR) loss, B=4096, D=256, N=8192, T=0.5.
// loss = [ sum_i log(sum_{j!=i} exp(sim_ij * 2)) - 4 * sum_{i<B} pos_i ] / N
// sim symmetric: upper-triangle 128x128 tiles only (2080 of 4096). Each tile
// emits row-sums for BOTH its row-range (DPP lane reduce -> colacc) and its
// col-range (per-lane reg reduce).
// Hybrid operand sourcing (r5 post-mortem): B-fragments live in 128 VGPRs,
// loaded ONCE per block (batched scatter, one wait); A-panel staged in LDS
// (coalesced DMA, double-buffered, KCH=64). k-loop = 2 ds_read + 4 MFMA per
// k-step -> DS demand ~5 us/CU < MFMA 7 us/CU (the pipe we want saturated).

constexpr int BB = 4096;                 // batch
constexpr int NN = 8192;                 // 2*batch
constexpr int DD = 256;                  // feature dim
constexpr int TS = 128;                  // tile edge
constexpr int NT = NN / TS;              // 64 tile rows/cols
constexpr int NBLK = NT * (NT + 1) / 2;  // 2080 = 8*260
constexpr int KCH = 64;                  // k-chunk (halfs): A panel 16 KB
constexpr int NCH = DD / KCH;            // 4 chunks

typedef _Float16 half4v __attribute__((ext_vector_type(4)));
typedef _Float16 half8v __attribute__((ext_vector_type(8)));
typedef float floatx16 __attribute__((ext_vector_type(16)));

// ---------------- Kernel 1: normalize rows -> f16, pos partials, zero rowsum -
__global__ __launch_bounds__(256) void nt_normalize(
    const float* __restrict__ zi, const float* __restrict__ zj,
    _Float16* __restrict__ Z, float* __restrict__ posPartial,
    float* __restrict__ rowsum)
{
    const int lane = threadIdx.x & 63;
    const int wave = threadIdx.x >> 6;
    const int i = blockIdx.x * 4 + wave;   // pair index, < BB

    if (blockIdx.x < 32) rowsum[blockIdx.x * 256 + threadIdx.x] = 0.f;

    const float4 a = ((const float4*)(zi + (size_t)i * DD))[lane];
    const float4 b = ((const float4*)(zj + (size_t)i * DD))[lane];

    float ssi = a.x*a.x + a.y*a.y + a.z*a.z + a.w*a.w;
    float ssj = b.x*b.x + b.y*b.y + b.z*b.z + b.w*b.w;
    float dd  = a.x*b.x + a.y*b.y + a.z*b.z + a.w*b.w;
#pragma unroll
    for (int off = 32; off > 0; off >>= 1) {
        ssi += __shfl_xor(ssi, off);
        ssj += __shfl_xor(ssj, off);
        dd  += __shfl_xor(dd,  off);
    }
    const float invi = rsqrtf(ssi);
    const float invj = rsqrtf(ssj);

    half4v ha, hb;
    ha.x = (_Float16)(a.x * invi); ha.y = (_Float16)(a.y * invi);
    ha.z = (_Float16)(a.z * invi); ha.w = (_Float16)(a.w * invi);
    hb.x = (_Float16)(b.x * invj); hb.y = (_Float16)(b.y * invj);
    hb.z = (_Float16)(b.z * invj); hb.w = (_Float16)(b.w * invj);

    ((half4v*)(Z + (size_t)i * DD))[lane]        = ha;
    ((half4v*)(Z + (size_t)(BB + i) * DD))[lane] = hb;

    __shared__ float ps[4];
    if (lane == 0) ps[wave] = dd * invi * invj;
    __syncthreads();
    if (threadIdx.x == 0)
        posPartial[blockIdx.x] = ps[0] + ps[1] + ps[2] + ps[3];
}

// DPP half-wave reduce: lane31 = sum(lanes 0..31), lane63 = sum(lanes 32..63).
__device__ __forceinline__ float half_sums(float x) {
    int t;
    t = __builtin_amdgcn_update_dpp(0, __builtin_bit_cast(int, x), 0x111, 0xf, 0xf, false);
    x += __builtin_bit_cast(float, t);
    t = __builtin_amdgcn_update_dpp(0, __builtin_bit_cast(int, x), 0x112, 0xf, 0xf, false);
    x += __builtin_bit_cast(float, t);
    t = __builtin_amdgcn_update_dpp(0, __builtin_bit_cast(int, x), 0x114, 0xf, 0xf, false);
    x += __builtin_bit_cast(float, t);
    t = __builtin_amdgcn_update_dpp(0, __builtin_bit_cast(int, x), 0x118, 0xf, 0xf, false);
    x += __builtin_bit_cast(float, t);
    t = __builtin_amdgcn_update_dpp(0, __builtin_bit_cast(int, x), 0x142, 0xa, 0xf, false);
    x += __builtin_bit_cast(float, t);
    return x;
}

// ---------------- Kernel 2: upper-tri sim-GEMM + exp + row/col sums ----------
// Grid: 2080 blocks x 256 thr (4 waves). Block (rt,ct): 128x128 tile.
// Wave (wr,wc) computes a 64x64 quadrant: 2x2 32x32 MFMA tiles.
// B-operand (wave's 64 c-rows, full K) in bfrag[2][16] = 128 VGPR, loaded once.
// A-panel staged in LDS, KCH=64, double-buffered: stage(ch+1) after barrier,
// compute(ch) from other buffer. launch_bounds(256,2): 256-reg cap, 8 waves/CU.
__global__ __launch_bounds__(256, 2) void nt_simexp(
    const _Float16* __restrict__ Z, float* __restrict__ rowsum)
{
    __shared__ _Float16 As[2][TS * KCH];   // 2 x 16 KB
    __shared__ float colacc[TS];           // 512 B

    // Bijective XCD swizzle (2080 % 8 == 0).
    const int bid = (blockIdx.x & 7) * (NBLK / 8) + (blockIdx.x >> 3);

    // Closed-form reverse-triangular map: t counts from the bottom row.
    const int t = NBLK - 1 - bid;
    int m = (int)((sqrtf((float)(8 * t + 1)) - 1.0f) * 0.5f);
    while ((m + 1) * (m + 2) / 2 <= t) ++m;   // fixup (+-1 from sqrt rounding)
    while (m * (m + 1) / 2 > t) --m;
    const int rt = NT - 1 - m;
    const int ct = NT - 1 - (t - m * (m + 1) / 2);
    const bool diag = (rt == ct);

    const int tid = threadIdx.x;
    const int wave = tid >> 6;
    const int lane = tid & 63;
    const int lm = lane & 31;
    const int lh = lane >> 5;
    const int wr = wave >> 1;           // row half (A side)
    const int wc = wave & 1;            // col half (B side)

    const int rbase = rt * TS;          // A-side rows (output rows)
    const int cbase = ct * TS;          // B-side rows (output cols)

    if (tid < TS) colacc[tid] = 0.f;    // visible after first k-loop barrier

    // A staging (verified r3 scheme, KCH=64): call c covers rows 8c..8c+7.
    // LDS[row][g] = SRC[row][g ^ (row&7)] via pre-swizzled global source,
    // linear LDS dest (global_load_lds requirement).
    const int st_row = lane >> 3;                 // 0..7
    const int st_sg  = (lane & 7) ^ (lane >> 3);  // source granule
    const _Float16* Ap = Z + (size_t)rbase * DD;
    auto stage = [&](int buf, int ch) {
#pragma unroll
        for (int j = 0; j < 4; ++j) {
            const int c = wave * 4 + j;           // 0..15
            const _Float16* g = Ap + (size_t)(8 * c + st_row) * DD
                                   + ch * KCH + st_sg * 8;
            __builtin_amdgcn_global_load_lds(
                (const __attribute__((address_space(1))) unsigned int*)g,
                (__attribute__((address_space(3))) unsigned int*)(&As[buf][c * 512]),
                16, 0, 0);
        }
    };

    stage(0, 0);                        // A chunk 0 DMA in flight

    // B-fragments: 32 independent 16B loads, issued back-to-back; the first
    // k-loop barrier's vmcnt(0) is the single wait. MFMA B layout: lane
    // (lm,lh) holds col lm, k = 16*ks + lh*8 + j  [verified r0-r5].
    const _Float16* br0 = Z + (size_t)(cbase + wc * 64 + lm) * DD + lh * 8;
    const _Float16* br1 = br0 + 32 * DD;
    half8v bfrag[2][16];
#pragma unroll
    for (int s = 0; s < 16; ++s) {
        bfrag[0][s] = *(const half8v*)(br0 + s * 16);
        bfrag[1][s] = *(const half8v*)(br1 + s * 16);
    }

    floatx16 a00, a01, a10, a11;
#pragma unroll
    for (int r = 0; r < 16; ++r) { a00[r] = 0.f; a01[r] = 0.f; a10[r] = 0.f; a11[r] = 0.f; }

#pragma unroll
    for (int ch = 0; ch < NCH; ++ch) {
        __syncthreads();   // drains vmcnt: chunk ch staged (and bfrag loaded);
                           // all waves done reading the buffer stage() reuses
        if (ch + 1 < NCH) stage((ch + 1) & 1, ch + 1);

        __builtin_amdgcn_s_setprio(1);
#pragma unroll
        for (int s = 0; s < 4; ++s) {
            const int ph = ((2 * s + lh) ^ (lm & 7)) * 8;   // phys granule off
            half8v fa0 = *(const half8v*)&As[ch & 1][(wr * 64 +      lm) * KCH + ph];
            half8v fa1 = *(const half8v*)&As[ch & 1][(wr * 64 + 32 + lm) * KCH + ph];
            const int ks = ch * 4 + s;
            a00 = __builtin_amdgcn_mfma_f32_32x32x16_f16(fa0, bfrag[0][ks], a00, 0, 0, 0);
            a01 = __builtin_amdgcn_mfma_f32_32x32x16_f16(fa0, bfrag[1][ks], a01, 0, 0, 0);
            a10 = __builtin_amdgcn_mfma_f32_32x32x16_f16(fa1, bfrag[0][ks], a10, 0, 0, 0);
            a11 = __builtin_amdgcn_mfma_f32_32x32x16_f16(fa1, bfrag[1][ks], a11, 0, 0, 0);
        }
        __builtin_amdgcn_s_setprio(0);
    }

    // Epilogue: e = exp2(sim * 2*log2e). Per-lane reg sums -> col-range rows
    // (B side, index lm); DPP across lm -> row-range rows (A side, index mrow).
    const float KEXP = 2.0f * 1.44269504088896340736f;
    float eb0 = 0.f, eb1 = 0.f;
#pragma unroll
    for (int tr = 0; tr < 2; ++tr) {
#pragma unroll
        for (int r = 0; r < 16; ++r) {
            const int mrow = (r & 3) + 8 * (r >> 2) + 4 * lh;
            float e0 = __builtin_amdgcn_exp2f((tr ? a10[r] : a00[r]) * KEXP);
            float e1 = __builtin_amdgcn_exp2f((tr ? a11[r] : a01[r]) * KEXP);
            // Diagonal element: global row == col -> wr==wc, tr==tc, mrow==lm.
            // e0 carries tc=0 (zero when tr==0), e1 carries tc=1 (when tr==1).
            if (diag && (wr == wc) && (mrow == lm)) {
                if (tr == 0) e0 = 0.f; else e1 = 0.f;
            }
            eb0 += e0; eb1 += e1;
            if (!diag) {
                float s2 = half_sums(e0 + e1);   // lanes 31/63 hold half-sums
                if (lm == 31)
                    atomicAdd(&colacc[wr * 64 + tr * 32 + mrow], s2);  // ds_add
            }
        }
    }

    eb0 += __shfl_xor(eb0, 32);
    eb1 += __shfl_xor(eb1, 32);
    if (lane < 32) {
        atomicAdd(&rowsum[cbase + wc * 64 + lm], eb0);
        atomicAdd(&rowsum[cbase + wc * 64 + 32 + lm], eb1);
    }
    if (!diag) {
        __syncthreads();
        if (tid < TS) atomicAdd(&rowsum[rbase + tid], colacc[tid]);
    }
}

// ---------------- Kernel 3: finalize ----------------------------------------
__global__ __launch_bounds__(256) void nt_finalize(
    const float* __restrict__ rowsum, const float* __restrict__ posPartial,
    float* __restrict__ out)
{
    const int tid = threadIdx.x;
    float acc = 0.f;
#pragma unroll
    for (int it = 0; it < NN / 256; ++it)
        acc += __builtin_amdgcn_logf(rowsum[tid + it * 256]);   // log2
    float pacc = 0.f;
#pragma unroll
    for (int it = 0; it < 4; ++it)
        pacc += posPartial[tid + it * 256];

#pragma unroll
    for (int off = 32; off > 0; off >>= 1) {
        acc  += __shfl_xor(acc,  off);
        pacc += __shfl_xor(pacc, off);
    }
    __shared__ float sa[4], sp[4];
    const int wave = tid >> 6;
    if ((tid & 63) == 0) { sa[wave] = acc; sp[wave] = pacc; }
    __syncthreads();
    if (tid == 0) {
        const float lntot = (sa[0] + sa[1] + sa[2] + sa[3]) * 0.6931471805599453f;
        const float ptot  = sp[0] + sp[1] + sp[2] + sp[3];
        out[0] = (lntot - 4.0f * ptot) * (1.0f / (float)NN);
    }
}

// ---------------- Launch ------------------------------------------------------
extern "C" void kernel_launch(void* const* d_in, const int* in_sizes, int n_in,
                              void* d_out, int out_size, void* d_ws, size_t ws_size,
                              hipStream_t stream) {
    const float* zi = (const float*)d_in[0];
    const float* zj = (const float*)d_in[1];
    float* out = (float*)d_out;

    _Float16* Z = (_Float16*)d_ws;                                  // 4 MB
    float* rowsum = (float*)((char*)d_ws + (size_t)NN * DD * 2);    // 32 KB
    float* posPartial = rowsum + NN;                                // 4 KB

    nt_normalize<<<BB / 4, 256, 0, stream>>>(zi, zj, Z, posPartial, rowsum);
    nt_simexp<<<NBLK, 256, 0, stream>>>((const _Float16*)Z, rowsum);
    nt_finalize<<<1, 256, 0, stream>>>(rowsum, posPartial, out);
}

// Round 7
// 102.820 us; speedup vs baseline: 1.2775x; 1.1475x over previous
//
#include <hip/hip_runtime.h>
#include <hip/hip_bf16.h>

// NT-Xent (SimCLR) loss, B=4096, D=256, N=8192, T=0.5.
// loss = [ sum_i log(sum_{j!=i} exp(sim_ij * 2)) - 4 * sum_{i<B} pos_i ] / N
// sim symmetric: upper-triangle 256x256 tiles (528 of 1024). 512-thread
// blocks, 8 waves (4 qr x 2 qc), each wave a 64x128 slice = 2x4 accs of
// 32x32x16 MFMA. Both panels staged in LDS (KCH=64, XOR row&7 swizzle via
// pre-swizzled global_load_lds source), double-buffered. Each tile emits
// row-sums for BOTH its col-range (per-lane reg sums) and row-range (DPP
// half_sums) into block-LDS accumulators, then one global atomic round.

constexpr int BB = 4096;                 // batch
constexpr int NN = 8192;                 // 2*batch
constexpr int DD = 256;                  // feature dim
constexpr int TS = 256;                  // tile edge
constexpr int NT = NN / TS;              // 32 tile rows/cols
constexpr int NBLK = NT * (NT + 1) / 2;  // 528 = 8*66
constexpr int KCH = 64;                  // k-chunk (halfs): panels 2x32 KB
constexpr int NCH = DD / KCH;            // 4 chunks

typedef _Float16 half4v __attribute__((ext_vector_type(4)));
typedef _Float16 half8v __attribute__((ext_vector_type(8)));
typedef float floatx16 __attribute__((ext_vector_type(16)));

// ---------------- Kernel 1: normalize rows -> f16, pos partials, zero rowsum -
__global__ __launch_bounds__(256) void nt_normalize(
    const float* __restrict__ zi, const float* __restrict__ zj,
    _Float16* __restrict__ Z, float* __restrict__ posPartial,
    float* __restrict__ rowsum)
{
    const int lane = threadIdx.x & 63;
    const int wave = threadIdx.x >> 6;
    const int i = blockIdx.x * 4 + wave;   // pair index, < BB

    if (blockIdx.x < 32) rowsum[blockIdx.x * 256 + threadIdx.x] = 0.f;

    const float4 a = ((const float4*)(zi + (size_t)i * DD))[lane];
    const float4 b = ((const float4*)(zj + (size_t)i * DD))[lane];

    float ssi = a.x*a.x + a.y*a.y + a.z*a.z + a.w*a.w;
    float ssj = b.x*b.x + b.y*b.y + b.z*b.z + b.w*b.w;
    float dd  = a.x*b.x + a.y*b.y + a.z*b.z + a.w*b.w;
#pragma unroll
    for (int off = 32; off > 0; off >>= 1) {
        ssi += __shfl_xor(ssi, off);
        ssj += __shfl_xor(ssj, off);
        dd  += __shfl_xor(dd,  off);
    }
    const float invi = rsqrtf(ssi);
    const float invj = rsqrtf(ssj);

    half4v ha, hb;
    ha.x = (_Float16)(a.x * invi); ha.y = (_Float16)(a.y * invi);
    ha.z = (_Float16)(a.z * invi); ha.w = (_Float16)(a.w * invi);
    hb.x = (_Float16)(b.x * invj); hb.y = (_Float16)(b.y * invj);
    hb.z = (_Float16)(b.z * invj); hb.w = (_Float16)(b.w * invj);

    ((half4v*)(Z + (size_t)i * DD))[lane]        = ha;
    ((half4v*)(Z + (size_t)(BB + i) * DD))[lane] = hb;

    __shared__ float ps[4];
    if (lane == 0) ps[wave] = dd * invi * invj;
    __syncthreads();
    if (threadIdx.x == 0)
        posPartial[blockIdx.x] = ps[0] + ps[1] + ps[2] + ps[3];
}

// DPP half-wave reduce: lane31 = sum(lanes 0..31), lane63 = sum(lanes 32..63).
__device__ __forceinline__ float half_sums(float x) {
    int t;
    t = __builtin_amdgcn_update_dpp(0, __builtin_bit_cast(int, x), 0x111, 0xf, 0xf, false);
    x += __builtin_bit_cast(float, t);
    t = __builtin_amdgcn_update_dpp(0, __builtin_bit_cast(int, x), 0x112, 0xf, 0xf, false);
    x += __builtin_bit_cast(float, t);
    t = __builtin_amdgcn_update_dpp(0, __builtin_bit_cast(int, x), 0x114, 0xf, 0xf, false);
    x += __builtin_bit_cast(float, t);
    t = __builtin_amdgcn_update_dpp(0, __builtin_bit_cast(int, x), 0x118, 0xf, 0xf, false);
    x += __builtin_bit_cast(float, t);
    t = __builtin_amdgcn_update_dpp(0, __builtin_bit_cast(int, x), 0x142, 0xa, 0xf, false);
    x += __builtin_bit_cast(float, t);
    return x;
}

// ---------------- Kernel 2: upper-tri sim-GEMM + exp + row/col sums ----------
// Grid: 528 blocks x 512 thr (8 waves). Block (rt,ct): 256x256 tile.
// Wave (qr,qc) = (wave>>1, wave&1)? no: (qr in 0..3) x (qc in 0..1), slice
// rows qr*64..+63, cols qc*128..+127: accs c[tr in 0..1][tc in 0..3].
// KCH=64 double-buffered both-panel staging (128 KB LDS, 1 block/CU).
__global__ __launch_bounds__(512, 2) void nt_simexp(
    const _Float16* __restrict__ Z, float* __restrict__ rowsum)
{
    __shared__ _Float16 As[2][TS * KCH];   // 2 x 32 KB
    __shared__ _Float16 Bs[2][TS * KCH];   // 2 x 32 KB
    __shared__ float rowaccA[TS];          // A-side (output-row) sums
    __shared__ float rowaccB[TS];          // B-side (output-col) sums

    // Bijective XCD swizzle (528 % 8 == 0).
    const int bid = (blockIdx.x & 7) * (NBLK / 8) + (blockIdx.x >> 3);

    // Closed-form reverse-triangular map.
    const int t = NBLK - 1 - bid;
    int m = (int)((sqrtf((float)(8 * t + 1)) - 1.0f) * 0.5f);
    while ((m + 1) * (m + 2) / 2 <= t) ++m;
    while (m * (m + 1) / 2 > t) --m;
    const int rt = NT - 1 - m;
    const int ct = NT - 1 - (t - m * (m + 1) / 2);
    const bool diag = (rt == ct);

    const int tid = threadIdx.x;
    const int wave = tid >> 6;
    const int lane = tid & 63;
    const int lm = lane & 31;
    const int lh = lane >> 5;
    const int qr = wave >> 1;           // 0..3: row slice (A side)
    const int qc = wave & 1;            // 0..1: col slice (B side)

    const int rbase = rt * TS;          // A-side rows (output rows)
    const int cbase = ct * TS;          // B-side rows (output cols)

    if (tid < TS) { rowaccA[tid] = 0.f; rowaccB[tid] = 0.f; }

    // Staging: per panel-chunk (256 rows x 128 B) -> 32 wave-wide 1 KB DMA
    // calls (8 rows x 8 granules each). Lane -> row 8c+(lane>>3), LDS granule
    // lane&7 (linear dest); source granule pre-swizzled so that
    // LDS[r][g] = SRC[r][g ^ (r&7)]   (r3-verified scheme).
    const int st_row = lane >> 3;                 // 0..7
    const int st_sg  = (lane & 7) ^ (lane >> 3);  // source granule
    const _Float16* Ap = Z + (size_t)rbase * DD;
    const _Float16* Bp = Z + (size_t)cbase * DD;

    auto stage = [&](int buf, int ch) {
        const int koff = ch * KCH;
#pragma unroll
        for (int j = 0; j < 4; ++j) {
            const int c = wave * 4 + j;           // 0..31
            const int r = 8 * c + st_row;
            __builtin_amdgcn_global_load_lds(
                (const __attribute__((address_space(1))) unsigned int*)
                    (Ap + (size_t)r * DD + koff + st_sg * 8),
                (__attribute__((address_space(3))) unsigned int*)(&As[buf][c * 512]),
                16, 0, 0);
            __builtin_amdgcn_global_load_lds(
                (const __attribute__((address_space(1))) unsigned int*)
                    (Bp + (size_t)r * DD + koff + st_sg * 8),
                (__attribute__((address_space(3))) unsigned int*)(&Bs[buf][c * 512]),
                16, 0, 0);
        }
    };

    floatx16 c00, c01, c02, c03, c10, c11, c12, c13;
#pragma unroll
    for (int r = 0; r < 16; ++r) {
        c00[r] = 0.f; c01[r] = 0.f; c02[r] = 0.f; c03[r] = 0.f;
        c10[r] = 0.f; c11[r] = 0.f; c12[r] = 0.f; c13[r] = 0.f;
    }

    stage(0, 0);

    for (int ch = 0; ch < NCH; ++ch) {
        __syncthreads();   // implicit vmcnt(0): chunk ch staged; all waves
                           // done reading the buffer stage() will overwrite
        if (ch + 1 < NCH) stage((ch + 1) & 1, ch + 1);

        const _Float16* As_ = As[ch & 1];
        const _Float16* Bs_ = Bs[ch & 1];
        __builtin_amdgcn_s_setprio(1);
#pragma unroll
        for (int ks = 0; ks < 4; ++ks) {
            const int ph = ((2 * ks + lh) ^ (lm & 7)) * 8;  // phys granule off
            const _Float16* ab = As_ + (qr * 64 + lm) * KCH + ph;
            half8v fa0 = *(const half8v*)ab;
            half8v fa1 = *(const half8v*)(ab + 32 * KCH);
            const _Float16* bb = Bs_ + (qc * 128 + lm) * KCH + ph;
            half8v fb0 = *(const half8v*)bb;
            half8v fb1 = *(const half8v*)(bb + 32 * KCH);
            half8v fb2 = *(const half8v*)(bb + 64 * KCH);
            half8v fb3 = *(const half8v*)(bb + 96 * KCH);
            c00 = __builtin_amdgcn_mfma_f32_32x32x16_f16(fa0, fb0, c00, 0, 0, 0);
            c01 = __builtin_amdgcn_mfma_f32_32x32x16_f16(fa0, fb1, c01, 0, 0, 0);
            c02 = __builtin_amdgcn_mfma_f32_32x32x16_f16(fa0, fb2, c02, 0, 0, 0);
            c03 = __builtin_amdgcn_mfma_f32_32x32x16_f16(fa0, fb3, c03, 0, 0, 0);
            c10 = __builtin_amdgcn_mfma_f32_32x32x16_f16(fa1, fb0, c10, 0, 0, 0);
            c11 = __builtin_amdgcn_mfma_f32_32x32x16_f16(fa1, fb1, c11, 0, 0, 0);
            c12 = __builtin_amdgcn_mfma_f32_32x32x16_f16(fa1, fb2, c12, 0, 0, 0);
            c13 = __builtin_amdgcn_mfma_f32_32x32x16_f16(fa1, fb3, c13, 0, 0, 0);
        }
        __builtin_amdgcn_s_setprio(0);
    }

    // Epilogue. Element (tr,tc,r): global row i = rbase + qr*64 + tr*32 + mrow,
    // col j = cbase + qc*128 + tc*32 + lm. exp2(sim*2*log2e); diag tiles mask
    // i==j and use B-side sums only (square tile covers both mirror halves).
    const float KEXP = 2.0f * 1.44269504088896340736f;
    float ebs0 = 0.f, ebs1 = 0.f, ebs2 = 0.f, ebs3 = 0.f;

#define EPI(CC, TC, EBS) { \
        float e = __builtin_amdgcn_exp2f(CC[r] * KEXP); \
        if (diag && (grow == qc * 128 + TC * 32 + lm)) e = 0.f; \
        EBS += e; rowpart += e; }

#pragma unroll
    for (int r = 0; r < 16; ++r) {
        const int mrow = (r & 3) + 8 * (r >> 2) + 4 * lh;
        {   // tr = 0
            const int grow = qr * 64 + mrow;
            float rowpart = 0.f;
            EPI(c00, 0, ebs0) EPI(c01, 1, ebs1) EPI(c02, 2, ebs2) EPI(c03, 3, ebs3)
            if (!diag) {
                float s2 = half_sums(rowpart);
                if (lm == 31) atomicAdd(&rowaccA[grow], s2);
            }
        }
        {   // tr = 1
            const int grow = qr * 64 + 32 + mrow;
            float rowpart = 0.f;
            EPI(c10, 0, ebs0) EPI(c11, 1, ebs1) EPI(c12, 2, ebs2) EPI(c13, 3, ebs3)
            if (!diag) {
                float s2 = half_sums(rowpart);
                if (lm == 31) atomicAdd(&rowaccA[grow], s2);
            }
        }
    }
#undef EPI

    // B-side: combine lane halves (mrow sets), one ds-atomic per col.
    ebs0 += __shfl_xor(ebs0, 32);
    ebs1 += __shfl_xor(ebs1, 32);
    ebs2 += __shfl_xor(ebs2, 32);
    ebs3 += __shfl_xor(ebs3, 32);
    if (lane < 32) {
        atomicAdd(&rowaccB[qc * 128 +      lm], ebs0);
        atomicAdd(&rowaccB[qc * 128 + 32 + lm], ebs1);
        atomicAdd(&rowaccB[qc * 128 + 64 + lm], ebs2);
        atomicAdd(&rowaccB[qc * 128 + 96 + lm], ebs3);
    }

    __syncthreads();
    if (tid < TS) {
        atomicAdd(&rowsum[cbase + tid], rowaccB[tid]);
        if (!diag) atomicAdd(&rowsum[rbase + tid], rowaccA[tid]);
    }
}

// ---------------- Kernel 3: finalize ----------------------------------------
__global__ __launch_bounds__(256) void nt_finalize(
    const float* __restrict__ rowsum, const float* __restrict__ posPartial,
    float* __restrict__ out)
{
    const int tid = threadIdx.x;
    float acc = 0.f;
#pragma unroll
    for (int it = 0; it < NN / 256; ++it)
        acc += __builtin_amdgcn_logf(rowsum[tid + it * 256]);   // log2
    float pacc = 0.f;
#pragma unroll
    for (int it = 0; it < 4; ++it)
        pacc += posPartial[tid + it * 256];

#pragma unroll
    for (int off = 32; off > 0; off >>= 1) {
        acc  += __shfl_xor(acc,  off);
        pacc += __shfl_xor(pacc, off);
    }
    __shared__ float sa[4], sp[4];
    const int wave = tid >> 6;
    if ((tid & 63) == 0) { sa[wave] = acc; sp[wave] = pacc; }
    __syncthreads();
    if (tid == 0) {
        const float lntot = (sa[0] + sa[1] + sa[2] + sa[3]) * 0.6931471805599453f;
        const float ptot  = sp[0] + sp[1] + sp[2] + sp[3];
        out[0] = (lntot - 4.0f * ptot) * (1.0f / (float)NN);
    }
}

// ---------------- Launch ------------------------------------------------------
extern "C" void kernel_launch(void* const* d_in, const int* in_sizes, int n_in,
                              void* d_out, int out_size, void* d_ws, size_t ws_size,
                              hipStream_t stream) {
    const float* zi = (const float*)d_in[0];
    const float* zj = (const float*)d_in[1];
    float* out = (float*)d_out;

    _Float16* Z = (_Float16*)d_ws;                                  // 4 MB
    float* rowsum = (float*)((char*)d_ws + (size_t)NN * DD * 2);    // 32 KB
    float* posPartial = rowsum + NN;                                // 4 KB

    nt_normalize<<<BB / 4, 256, 0, stream>>>(zi, zj, Z, posPartial, rowsum);
    nt_simexp<<<NBLK, 512, 0, stream>>>((const _Float16*)Z, rowsum);
    nt_finalize<<<1, 256, 0, stream>>>(rowsum, posPartial, out);
}

// Round 8
// 91.666 us; speedup vs baseline: 1.4329x; 1.1217x over previous
//
#include <hip/hip_runtime.h>
#include <hip/hip_bf16.h>

// NT-Xent (SimCLR) loss, B=4096, D=256, N=8192, T=0.5.
// loss = [ sum_i log(sum_{j!=i} exp(sim_ij * 2)) - 4 * sum_{i<B} pos_i ] / N
// sim symmetric: upper-triangle 128x128 tiles (2080 of 4096).
// KEY STRUCTURE (r7 post-mortem): normalize writes Z in MFMA-FRAGMENT ORDER
// (Zf: granule gi = (g*16+ks)*64 + lm + 32*lh holds halfs [16ks+8lh,+8) of
// row 32g+lm). simexp then streams operands with perfectly-coalesced 1KB
// wave loads straight from L2 -> NO LDS staging, NO k-loop barriers, fully
// independent waves, 4 blocks/CU of TLP. Epilogue (exp2 + per-lane B-side
// sums + DPP A-side sums + diagonal mask) is the r5-verified code verbatim.

constexpr int BB = 4096;                 // batch
constexpr int NN = 8192;                 // 2*batch
constexpr int DD = 256;                  // feature dim
constexpr int TS = 128;                  // tile edge
constexpr int NT = NN / TS;              // 64 tile rows/cols
constexpr int NBLK = NT * (NT + 1) / 2;  // 2080 = 8*260
constexpr int KSTEPS = DD / 16;          // 16 MFMA k-steps

typedef _Float16 half4v __attribute__((ext_vector_type(4)));
typedef _Float16 half8v __attribute__((ext_vector_type(8)));
typedef float floatx16 __attribute__((ext_vector_type(16)));

// ---------------- Kernel 1: normalize -> fragment-ordered f16, pos, zero ----
// Block b (128 blocks, 256 thr): pairs p = 32b..32b+31 -> full row-group b
// (zi half) and group 128+b (zj half). 8 threads per row; granules staged in
// LDS then written out fully coalesced (16B/thread).
__global__ __launch_bounds__(256) void nt_normalize(
    const float* __restrict__ zi, const float* __restrict__ zj,
    _Float16* __restrict__ Zf, float* __restrict__ pos,
    float* __restrict__ rowsum)
{
    __shared__ _Float16 sZ[2][16 * 64 * 8];   // 2 groups x 1024 granules = 32 KB
    const int tid = threadIdx.x;
    const int pr  = tid >> 3;     // row within group, 0..31
    const int sub = tid & 7;      // 8 threads per row
    const int p   = blockIdx.x * 32 + pr;     // pair index, < BB

    if (blockIdx.x < 32) rowsum[blockIdx.x * 256 + tid] = 0.f;

    // Thread loads float4s at positions sub + 8t: per-instruction the wave
    // covers 8 rows x 128B contiguous each (well coalesced).
    const float4* ai = (const float4*)(zi + (size_t)p * DD);
    const float4* bj = (const float4*)(zj + (size_t)p * DD);
    float4 av[8], bv[8];
    float ssi = 0.f, ssj = 0.f, dd = 0.f;
#pragma unroll
    for (int t = 0; t < 8; ++t) {
        av[t] = ai[sub + 8 * t];
        bv[t] = bj[sub + 8 * t];
        ssi += av[t].x*av[t].x + av[t].y*av[t].y + av[t].z*av[t].z + av[t].w*av[t].w;
        ssj += bv[t].x*bv[t].x + bv[t].y*bv[t].y + bv[t].z*bv[t].z + bv[t].w*bv[t].w;
        dd  += av[t].x*bv[t].x + av[t].y*bv[t].y + av[t].z*bv[t].z + av[t].w*bv[t].w;
    }
#pragma unroll
    for (int off = 1; off < 8; off <<= 1) {   // reduce across the 8 sub-lanes
        ssi += __shfl_xor(ssi, off);
        ssj += __shfl_xor(ssj, off);
        dd  += __shfl_xor(dd,  off);
    }
    const float invi = rsqrtf(ssi);
    const float invj = rsqrtf(ssj);
    if (sub == 0) pos[p] = dd * invi * invj;

    // Thread's halfs: k = 32t + 4sub + c. Granule j = 4t + (sub>>1);
    // ks = 2t + (sub>>2); lh = (sub>>1)&1; within-granule off = 4*(sub&1).
    // Dest granule (local): gi = ks*64 + pr + 32*lh.
#pragma unroll
    for (int t = 0; t < 8; ++t) {
        const int gi = (2 * t + (sub >> 2)) * 64 + pr + 32 * ((sub >> 1) & 1);
        const int wo = 4 * (sub & 1);
        half4v hi, hj;
        hi.x = (_Float16)(av[t].x * invi); hi.y = (_Float16)(av[t].y * invi);
        hi.z = (_Float16)(av[t].z * invi); hi.w = (_Float16)(av[t].w * invi);
        hj.x = (_Float16)(bv[t].x * invj); hj.y = (_Float16)(bv[t].y * invj);
        hj.z = (_Float16)(bv[t].z * invj); hj.w = (_Float16)(bv[t].w * invj);
        *(half4v*)&sZ[0][gi * 8 + wo] = hi;
        *(half4v*)&sZ[1][gi * 8 + wo] = hj;
    }
    __syncthreads();

    // Coalesced write-out: group b (zi rows) and group 128+b (zj rows).
    float4* Zf4 = (float4*)Zf;
    const float4* s0 = (const float4*)sZ[0];
    const float4* s1 = (const float4*)sZ[1];
    const size_t gbi = (size_t)blockIdx.x * 1024;
    const size_t gbj = (size_t)(128 + blockIdx.x) * 1024;
#pragma unroll
    for (int it = 0; it < 4; ++it) {
        Zf4[gbi + tid + it * 256] = s0[tid + it * 256];
        Zf4[gbj + tid + it * 256] = s1[tid + it * 256];
    }
}

// DPP half-wave reduce: lane31 = sum(lanes 0..31), lane63 = sum(lanes 32..63).
__device__ __forceinline__ float half_sums(float x) {
    int t;
    t = __builtin_amdgcn_update_dpp(0, __builtin_bit_cast(int, x), 0x111, 0xf, 0xf, false);
    x += __builtin_bit_cast(float, t);
    t = __builtin_amdgcn_update_dpp(0, __builtin_bit_cast(int, x), 0x112, 0xf, 0xf, false);
    x += __builtin_bit_cast(float, t);
    t = __builtin_amdgcn_update_dpp(0, __builtin_bit_cast(int, x), 0x114, 0xf, 0xf, false);
    x += __builtin_bit_cast(float, t);
    t = __builtin_amdgcn_update_dpp(0, __builtin_bit_cast(int, x), 0x118, 0xf, 0xf, false);
    x += __builtin_bit_cast(float, t);
    t = __builtin_amdgcn_update_dpp(0, __builtin_bit_cast(int, x), 0x142, 0xa, 0xf, false);
    x += __builtin_bit_cast(float, t);
    return x;
}

// ---------------- Kernel 2: upper-tri sim-GEMM + exp + row/col sums ----------
// Grid: 2080 blocks x 256 thr (4 waves). Block (rt,ct): 128x128 tile.
// Wave (wr,wc) computes a 64x64 quadrant: 2x2 accs of 32x32x16 MFMA.
// Per k-step: 4 coalesced 1KB fragment loads from Zf + 4 MFMAs. 1-deep
// register prefetch; no LDS, no barriers in the k-loop.
__global__ __launch_bounds__(256, 4) void nt_simexp(
    const _Float16* __restrict__ Zf, float* __restrict__ rowsum)
{
    __shared__ float colacc[TS];               // 512 B (only LDS use)

    // Bijective XCD swizzle (2080 % 8 == 0).
    const int bid = (blockIdx.x & 7) * (NBLK / 8) + (blockIdx.x >> 3);

    // Closed-form reverse-triangular map.
    const int t = NBLK - 1 - bid;
    int m = (int)((sqrtf((float)(8 * t + 1)) - 1.0f) * 0.5f);
    while ((m + 1) * (m + 2) / 2 <= t) ++m;
    while (m * (m + 1) / 2 > t) --m;
    const int rt = NT - 1 - m;
    const int ct = NT - 1 - (t - m * (m + 1) / 2);
    const bool diag = (rt == ct);

    const int tid = threadIdx.x;
    const int wave = tid >> 6;
    const int lane = tid & 63;
    const int lm = lane & 31;
    const int lh = lane >> 5;
    const int wr = wave >> 1;           // row half (A side)
    const int wc = wave & 1;            // col half (B side)

    const int rbase = rt * TS;          // A-side rows (output rows)
    const int cbase = ct * TS;          // B-side rows (output cols)

    if (tid < TS) colacc[tid] = 0.f;
    __syncthreads();                    // colacc init visible before epilogue

    // Fragment streams: row-groups of 32; wave's quadrant = 2 groups per side.
    const int ga0 = (rbase >> 5) + wr * 2;
    const int gb0 = (cbase >> 5) + wc * 2;
    const half8v* pa0 = (const half8v*)Zf + (size_t)ga0 * 1024 + lane;
    const half8v* pa1 = pa0 + 1024;
    const half8v* pb0 = (const half8v*)Zf + (size_t)gb0 * 1024 + lane;
    const half8v* pb1 = pb0 + 1024;

    floatx16 a00, a01, a10, a11;
#pragma unroll
    for (int r = 0; r < 16; ++r) { a00[r] = 0.f; a01[r] = 0.f; a10[r] = 0.f; a11[r] = 0.f; }

    half8v fa0 = pa0[0], fa1 = pa1[0], fb0 = pb0[0], fb1 = pb1[0];
#pragma unroll
    for (int ks = 0; ks < KSTEPS; ++ks) {
        half8v na0 = fa0, na1 = fa1, nb0 = fb0, nb1 = fb1;
        if (ks + 1 < KSTEPS) {
            na0 = pa0[(ks + 1) * 64];
            na1 = pa1[(ks + 1) * 64];
            nb0 = pb0[(ks + 1) * 64];
            nb1 = pb1[(ks + 1) * 64];
        }
        a00 = __builtin_amdgcn_mfma_f32_32x32x16_f16(fa0, fb0, a00, 0, 0, 0);
        a01 = __builtin_amdgcn_mfma_f32_32x32x16_f16(fa0, fb1, a01, 0, 0, 0);
        a10 = __builtin_amdgcn_mfma_f32_32x32x16_f16(fa1, fb0, a10, 0, 0, 0);
        a11 = __builtin_amdgcn_mfma_f32_32x32x16_f16(fa1, fb1, a11, 0, 0, 0);
        fa0 = na0; fa1 = na1; fb0 = nb0; fb1 = nb1;
    }

    // Epilogue (r5-verified verbatim): e = exp2(sim * 2*log2e). Per-lane reg
    // sums -> col-range rows (B side, lm); DPP -> row-range rows (A side).
    const float KEXP = 2.0f * 1.44269504088896340736f;
    float eb0 = 0.f, eb1 = 0.f;
#pragma unroll
    for (int tr = 0; tr < 2; ++tr) {
#pragma unroll
        for (int r = 0; r < 16; ++r) {
            const int mrow = (r & 3) + 8 * (r >> 2) + 4 * lh;
            float e0 = __builtin_amdgcn_exp2f((tr ? a10[r] : a00[r]) * KEXP);
            float e1 = __builtin_amdgcn_exp2f((tr ? a11[r] : a01[r]) * KEXP);
            // Diagonal element: global row == col -> wr==wc, tr==tc, mrow==lm.
            if (diag && (wr == wc) && (mrow == lm)) {
                if (tr == 0) e0 = 0.f; else e1 = 0.f;
            }
            eb0 += e0; eb1 += e1;
            if (!diag) {
                float s2 = half_sums(e0 + e1);   // lanes 31/63 hold half-sums
                if (lm == 31)
                    atomicAdd(&colacc[wr * 64 + tr * 32 + mrow], s2);  // ds_add
            }
        }
    }

    eb0 += __shfl_xor(eb0, 32);
    eb1 += __shfl_xor(eb1, 32);
    if (lane < 32) {
        atomicAdd(&rowsum[cbase + wc * 64 + lm], eb0);
        atomicAdd(&rowsum[cbase + wc * 64 + 32 + lm], eb1);
    }
    if (!diag) {
        __syncthreads();
        if (tid < TS) atomicAdd(&rowsum[rbase + tid], colacc[tid]);
    }
}

// ---------------- Kernel 3: finalize ----------------------------------------
__global__ __launch_bounds__(256) void nt_finalize(
    const float* __restrict__ rowsum, const float* __restrict__ pos,
    float* __restrict__ out)
{
    const int tid = threadIdx.x;
    float acc = 0.f;
#pragma unroll
    for (int it = 0; it < NN / 256; ++it)
        acc += __builtin_amdgcn_logf(rowsum[tid + it * 256]);   // log2
    float pacc = 0.f;
#pragma unroll
    for (int it = 0; it < BB / 256; ++it)
        pacc += pos[tid + it * 256];

#pragma unroll
    for (int off = 32; off > 0; off >>= 1) {
        acc  += __shfl_xor(acc,  off);
        pacc += __shfl_xor(pacc, off);
    }
    __shared__ float sa[4], sp[4];
    const int wave = tid >> 6;
    if ((tid & 63) == 0) { sa[wave] = acc; sp[wave] = pacc; }
    __syncthreads();
    if (tid == 0) {
        const float lntot = (sa[0] + sa[1] + sa[2] + sa[3]) * 0.6931471805599453f;
        const float ptot  = sp[0] + sp[1] + sp[2] + sp[3];
        out[0] = (lntot - 4.0f * ptot) * (1.0f / (float)NN);
    }
}

// ---------------- Launch ------------------------------------------------------
extern "C" void kernel_launch(void* const* d_in, const int* in_sizes, int n_in,
                              void* d_out, int out_size, void* d_ws, size_t ws_size,
                              hipStream_t stream) {
    const float* zi = (const float*)d_in[0];
    const float* zj = (const float*)d_in[1];
    float* out = (float*)d_out;

    _Float16* Zf = (_Float16*)d_ws;                                 // 4 MB
    float* rowsum = (float*)((char*)d_ws + (size_t)NN * DD * 2);    // 32 KB
    float* pos = rowsum + NN;                                       // 16 KB

    nt_normalize<<<BB / 32, 256, 0, stream>>>(zi, zj, Zf, pos, rowsum);
    nt_simexp<<<NBLK, 256, 0, stream>>>((const _Float16*)Zf, rowsum);
    nt_finalize<<<1, 256, 0, stream>>>(rowsum, pos, out);
}